// Round 5
// baseline (291.184 us; speedup 1.0000x reference)
//
#include <hip/hip_runtime.h>

// Shapes: B=1, S=128, Q=256, C=256, H=8, DH=32, TOT=256. Inputs/out f32.
// Intermediates bf16 in d_ws. Numerics bit-identical to R2-R4 (absmax
// 0.01953125 vs thr 0.019609): RNE cvt, ascending-k MFMA accumulation,
// identical softmax op order. XCD rule: consecutive blockIdx -> different
// XCDs; data-sharing siblings must be ≡ (mod 8) apart in linear order.

typedef unsigned short u16;
typedef unsigned int   u32;
typedef float  f32x4  __attribute__((ext_vector_type(4)));
typedef __bf16 bf16x8 __attribute__((ext_vector_type(8)));

__device__ __forceinline__ float bf2f(u16 u) {
    union { u32 i; float f; } v; v.i = ((u32)u) << 16; return v.f;
}
__device__ __forceinline__ u16 f2bf(float f) {      // hw RNE cvt
    __bf16 h = (__bf16)f; return __builtin_bit_cast(u16, h);
}

// ---- staging: 16 contiguous elems -> bf16 regs ----
__device__ __forceinline__ void load16_bf16(const float* src, u16* dst) {
    const float4* p = (const float4*)src;
    float4 f0 = p[0], f1 = p[1], f2 = p[2], f3 = p[3];
    dst[0]  = f2bf(f0.x); dst[1]  = f2bf(f0.y); dst[2]  = f2bf(f0.z); dst[3]  = f2bf(f0.w);
    dst[4]  = f2bf(f1.x); dst[5]  = f2bf(f1.y); dst[6]  = f2bf(f1.z); dst[7]  = f2bf(f1.w);
    dst[8]  = f2bf(f2.x); dst[9]  = f2bf(f2.y); dst[10] = f2bf(f2.z); dst[11] = f2bf(f2.w);
    dst[12] = f2bf(f3.x); dst[13] = f2bf(f3.y); dst[14] = f2bf(f3.z); dst[15] = f2bf(f3.w);
}
__device__ __forceinline__ void load16_bf16(const u16* src, u16* dst) {
    const uint4* p = (const uint4*)src;
    uint4 a0 = p[0], a1 = p[1];
    *(uint4*)&dst[0] = a0; *(uint4*)&dst[8] = a1;
}
__device__ __forceinline__ void store_out(float* p, float v) { *p = v; }
__device__ __forceinline__ void store_out(u16*   p, float v) { *p = f2bf(v); }

// -------------------------------------------------------------------------
// LDS-staged GEMM core, BK=64 (4 iters, 2x MLP, half the barriers of BK=32).
// C[m,n] = act(sum_k A[m,k]*W[n,k] + bias[n]).  Block tile BM x 128; 4 waves
// 2x2; wave tile (BM/2) x 64.  MFMA k-order ascending == BK=32 order.
// LDS stride 72 u16 = 36 dwords: fragment b128 reads hit each bank exactly
// 8x (the b128 floor) -> conflict-free in throughput terms.
// -------------------------------------------------------------------------
template <typename TA, typename TO, int BM>
__device__ __forceinline__ void gemm_k64(
    const TA* __restrict__ A, const float* __restrict__ W,
    const float* __restrict__ bias, TO* __restrict__ out, int act,
    int m0, int n0, int tid)
{
    __shared__ u16 At[BM][72];
    __shared__ u16 Wt[128][72];

    const int lane = tid & 63;
    const int w    = tid >> 6;
    const int quad = lane >> 4;
    const int ln   = lane & 15;
    const int wm   = (w >> 1) * (BM / 2);
    const int wn   = (w & 1) * 64;
    const int MI   = BM / 32;          // 4 (BM=128) or 2 (BM=64) m-frags

    const int ra = (BM == 128) ? (tid >> 1) : (tid >> 2);
    const int ca = (BM == 128) ? ((tid & 1) * 32) : ((tid & 3) * 16);
    const int rw = tid >> 1;
    const int cw = (tid & 1) * 32;

    f32x4 acc[4][4] = {};

    for (int k0 = 0; k0 < 256; k0 += 64) {
        u16 ta[32], tw[32];
        load16_bf16(A + (size_t)(m0 + ra) * 256 + k0 + ca, ta);
        if (BM == 128)
            load16_bf16(A + (size_t)(m0 + ra) * 256 + k0 + ca + 16, ta + 16);
        load16_bf16(W + (size_t)(n0 + rw) * 256 + k0 + cw, tw);
        load16_bf16(W + (size_t)(n0 + rw) * 256 + k0 + cw + 16, tw + 16);

        __syncthreads();               // prev iter's LDS reads drained
        *(uint4*)&At[ra][ca]      = *(uint4*)&ta[0];
        *(uint4*)&At[ra][ca + 8]  = *(uint4*)&ta[8];
        if (BM == 128) {
            *(uint4*)&At[ra][ca + 16] = *(uint4*)&ta[16];
            *(uint4*)&At[ra][ca + 24] = *(uint4*)&ta[24];
        }
        *(uint4*)&Wt[rw][cw]      = *(uint4*)&tw[0];
        *(uint4*)&Wt[rw][cw + 8]  = *(uint4*)&tw[8];
        *(uint4*)&Wt[rw][cw + 16] = *(uint4*)&tw[16];
        *(uint4*)&Wt[rw][cw + 24] = *(uint4*)&tw[24];
        __syncthreads();

        #pragma unroll
        for (int kk = 0; kk < 2; ++kk) {           // k ascending within chunk
            const int kc = kk * 32 + quad * 8;
            bf16x8 af[4], bfr[4];
            #pragma unroll
            for (int i = 0; i < MI; ++i)
                af[i] = __builtin_bit_cast(bf16x8, *(const uint4*)&At[wm + i * 16 + ln][kc]);
            #pragma unroll
            for (int j = 0; j < 4; ++j)
                bfr[j] = __builtin_bit_cast(bf16x8, *(const uint4*)&Wt[wn + j * 16 + ln][kc]);
            #pragma unroll
            for (int i = 0; i < MI; ++i)
                #pragma unroll
                for (int j = 0; j < 4; ++j)
                    acc[i][j] = __builtin_amdgcn_mfma_f32_16x16x32_bf16(af[i], bfr[j], acc[i][j], 0, 0, 0);
        }
    }

    #pragma unroll
    for (int i = 0; i < 4; ++i) {
        if (i >= MI) break;
        #pragma unroll
        for (int j = 0; j < 4; ++j) {
            #pragma unroll
            for (int rr = 0; rr < 4; ++rr) {
                const int row = m0 + wm + i * 16 + quad * 4 + rr;  // C/D row=quad*4+reg
                const int col = n0 + wn + j * 16 + ln;             //     col=lane&15
                float v = acc[i][j][rr];
                if (bias) v += bias[col];
                if (act)  v = 1.0f / (1.0f + __expf(-v));
                store_out(&out[(size_t)row * 256 + col], v);
            }
        }
    }
}

// Pass 1: fused Q/K/V/G projections, 2048 blocks.
// Swizzle: mb = bid&255 (XCD = mb%8), nb = bid>>8 -> the 8 blocks sharing an
// A m-tile sit 256 apart == same XCD -> A fetched once per XCD L2.
__global__ __launch_bounds__(256, 2) void proj_all(
    const float* __restrict__ qx, const float* __restrict__ kvx,
    const float* __restrict__ Wq, const float* __restrict__ Wk,
    const float* __restrict__ Wv, const float* __restrict__ Wg,
    const float* __restrict__ bg,
    u16* __restrict__ Qb, u16* __restrict__ Kb, u16* __restrict__ Vb, u16* __restrict__ Gb)
{
    const int bid = blockIdx.x;
    const int mb  = bid & 255;
    const int nb  = bid >> 8;
    const int t   = nb >> 1;               // 0=Q 1=K 2=V 3=G
    const int n0  = (nb & 1) * 128;
    const int m0  = mb * 128;
    const float* A = (t == 0 || t == 3) ? qx : kvx;
    const float* W = (t == 0) ? Wq : (t == 1) ? Wk : (t == 2) ? Wv : Wg;
    u16*         O = (t == 0) ? Qb : (t == 1) ? Kb : (t == 2) ? Vb : Gb;
    gemm_k64<float, u16, 128>(A, W, (t == 3) ? bg : (const float*)nullptr, O, t == 3, m0, n0, threadIdx.x);
}

// Pass 3: output projection (+bo) to f32. BM=64 -> 1024 blocks (~4-5/CU).
// Swizzle: mb = bid&511 -> the 2 n-siblings sharing an A tile sit 512 apart
// == same XCD.
__global__ __launch_bounds__(256, 2) void gemm_out(
    const u16* __restrict__ Ob, const float* __restrict__ Wo,
    const float* __restrict__ bo, float* __restrict__ out)
{
    const int bid = blockIdx.x;
    const int m0  = (bid & 511) * 64;
    const int n0  = (bid >> 9) * 128;
    gemm_k64<u16, float, 64>(Ob, Wo, bo, out, 0, m0, n0, threadIdx.x);
}

// -------------------------------------------------------------------------
// Pass 2: attention, R2 shape (max TLP: 4096 blocks, one 16-row m-tile per
// wave) + XCD swizzle: grid (1024 hs, 4 qt) -> qt-siblings of one (h,s) sit
// 1024 apart == same XCD, so the 4x K/V re-fetch is served by XCD L2.
// -------------------------------------------------------------------------
__global__ __launch_bounds__(256) void attn_kernel(
    const u16* __restrict__ Qb, const u16* __restrict__ Kb, const u16* __restrict__ Vb,
    const u16* __restrict__ Gb, const float* __restrict__ bm, const float* __restrict__ bp,
    u16* __restrict__ Ob)
{
    __shared__ u16   Vt[32][264];       // V transposed: Vt[dh][kp]
    __shared__ u16   Pl[4][16][268];    // per-wave P tile
    __shared__ float bmf[256];

    const int hs   = blockIdx.x;
    const int h    = hs & 7;
    const int s    = hs >> 3;
    const int qt   = blockIdx.y;
    const int tid  = threadIdx.x;
    const int lane = tid & 63;
    const int w    = tid >> 6;
    const int quad = lane >> 4;
    const int ln   = lane & 15;

    {   // stage V^T (thread tid = key row) + bias_mask
        const uint4* vp = (const uint4*)(Vb + (size_t)(s * 256 + tid) * 256 + h * 32);
        uint4 vv0 = vp[0], vv1 = vp[1], vv2 = vp[2], vv3 = vp[3];
        u16 tmp[32];
        *(uint4*)&tmp[0]  = vv0; *(uint4*)&tmp[8]  = vv1;
        *(uint4*)&tmp[16] = vv2; *(uint4*)&tmp[24] = vv3;
        #pragma unroll
        for (int dh = 0; dh < 32; ++dh) Vt[dh][tid] = tmp[dh];
        bmf[tid] = bm[s * 256 + tid];
    }
    __syncthreads();

    const int q0 = qt * 64 + w * 16;

    bf16x8 aq = __builtin_bit_cast(bf16x8,
        *(const uint4*)(Qb + (size_t)(s * 256 + q0 + ln) * 256 + h * 32 + quad * 8));

    f32x4 sc[16];
    #pragma unroll
    for (int nt = 0; nt < 16; ++nt) {
        bf16x8 bk = __builtin_bit_cast(bf16x8,
            *(const uint4*)(Kb + (size_t)(s * 256 + nt * 16 + ln) * 256 + h * 32 + quad * 8));
        f32x4 z = {0.f, 0.f, 0.f, 0.f};
        sc[nt] = __builtin_amdgcn_mfma_f32_16x16x32_bf16(aq, bk, z, 0, 0, 0);
    }

    float rmax[4] = {-1e30f, -1e30f, -1e30f, -1e30f};
    #pragma unroll
    for (int nt = 0; nt < 16; ++nt) {
        const int kp = nt * 16 + ln;
        const float bmv = bmf[kp];
        #pragma unroll
        for (int rr = 0; rr < 4; ++rr) {
            const int q = q0 + quad * 4 + rr;
            float v = sc[nt][rr] + bmv + bp[(size_t)(h * 256 + q) * 256 + kp];
            sc[nt][rr] = v;
            rmax[rr] = fmaxf(rmax[rr], v);
        }
    }
    #pragma unroll
    for (int rr = 0; rr < 4; ++rr) {
        float m = rmax[rr];
        m = fmaxf(m, __shfl_xor(m, 1));
        m = fmaxf(m, __shfl_xor(m, 2));
        m = fmaxf(m, __shfl_xor(m, 4));
        m = fmaxf(m, __shfl_xor(m, 8));
        rmax[rr] = m;
    }
    float rsum[4] = {0.f, 0.f, 0.f, 0.f};
    #pragma unroll
    for (int nt = 0; nt < 16; ++nt)
        #pragma unroll
        for (int rr = 0; rr < 4; ++rr) {
            float p = __expf(sc[nt][rr] - rmax[rr]);
            sc[nt][rr] = p;
            rsum[rr] += p;
        }
    float rinv[4];
    #pragma unroll
    for (int rr = 0; rr < 4; ++rr) {
        float t = rsum[rr];
        t += __shfl_xor(t, 1);
        t += __shfl_xor(t, 2);
        t += __shfl_xor(t, 4);
        t += __shfl_xor(t, 8);
        rinv[rr] = 1.0f / t;
    }

    #pragma unroll
    for (int nt = 0; nt < 16; ++nt)
        #pragma unroll
        for (int rr = 0; rr < 4; ++rr)
            Pl[w][quad * 4 + rr][nt * 16 + ln] = f2bf(sc[nt][rr] * rinv[rr]);

    f32x4 o0 = {0.f, 0.f, 0.f, 0.f}, o1 = {0.f, 0.f, 0.f, 0.f};
    #pragma unroll
    for (int kc = 0; kc < 8; ++kc) {
        bf16x8 pa = __builtin_bit_cast(bf16x8, *(const uint4*)&Pl[w][ln][kc * 32 + quad * 8]);
        bf16x8 v0 = __builtin_bit_cast(bf16x8, *(const uint4*)&Vt[ln][kc * 32 + quad * 8]);
        bf16x8 v1 = __builtin_bit_cast(bf16x8, *(const uint4*)&Vt[16 + ln][kc * 32 + quad * 8]);
        o0 = __builtin_amdgcn_mfma_f32_16x16x32_bf16(pa, v0, o0, 0, 0, 0);
        o1 = __builtin_amdgcn_mfma_f32_16x16x32_bf16(pa, v1, o1, 0, 0, 0);
    }

    #pragma unroll
    for (int rr = 0; rr < 4; ++rr) {
        const int q = q0 + quad * 4 + rr;
        const size_t base = (size_t)(s * 256 + q) * 256 + h * 32;
        float g0 = bf2f(Gb[base + ln]);
        float g1 = bf2f(Gb[base + 16 + ln]);
        Ob[base + ln]      = f2bf(o0[rr] * g0);
        Ob[base + 16 + ln] = f2bf(o1[rr] * g1);
    }
}

// -------------------------------------------------------------------------
extern "C" void kernel_launch(void* const* d_in, const int* in_sizes, int n_in,
                              void* d_out, int out_size, void* d_ws, size_t ws_size,
                              hipStream_t stream)
{
    const float* qx  = (const float*)d_in[0];
    const float* kvx = (const float*)d_in[1];
    const float* bm  = (const float*)d_in[2];
    const float* bp  = (const float*)d_in[3];
    const float* Wq  = (const float*)d_in[4];
    const float* Wk  = (const float*)d_in[5];
    const float* Wv  = (const float*)d_in[6];
    const float* Wg  = (const float*)d_in[7];
    const float* bg  = (const float*)d_in[8];
    const float* Wo  = (const float*)d_in[9];
    const float* bo  = (const float*)d_in[10];
    float* out = (float*)d_out;

    // ws: 5 bf16 buffers of 32768x256 = 83.9 MB
    const size_t NEL = (size_t)32768 * 256;
    u16* Qb = (u16*)d_ws;
    u16* Kb = Qb + NEL;
    u16* Vb = Kb + NEL;
    u16* Gb = Vb + NEL;
    u16* Ob = Gb + NEL;

    proj_all<<<dim3(2048), dim3(256), 0, stream>>>(qx, kvx, Wq, Wk, Wv, Wg, bg, Qb, Kb, Vb, Gb);

    attn_kernel<<<dim3(1024, 4), dim3(256), 0, stream>>>(Qb, Kb, Vb, Gb, bm, bp, Ob);

    gemm_out<<<dim3(1024), dim3(256), 0, stream>>>(Ob, Wo, bo, out);
}

// Round 6
// 250.141 us; speedup vs baseline: 1.1641x; 1.1641x over previous
//
#include <hip/hip_runtime.h>

// Shapes: B=1, S=128, Q=256, C=256, H=8, DH=32, TOT=256. Inputs/out f32.
// Numerics bit-identical to R2-R5 (absmax 0.01953125 vs thr 0.019609):
// RNE f32->bf16 once in prep, ascending-k MFMA accumulation, identical
// softmax op order. GEMMs use m97 structure: global_load_lds width=16,
// unpadded LDS tiles, 2-barrier K-loop.
// XCD rule: consecutive blockIdx -> different XCDs; data-sharing siblings
// placed ≡ (mod 8) apart in linear order.

typedef unsigned short u16;
typedef unsigned int   u32;
typedef float  f32x4  __attribute__((ext_vector_type(4)));
typedef __bf16 bf16x8 __attribute__((ext_vector_type(8)));

__device__ __forceinline__ float bf2f(u16 u) {
    union { u32 i; float f; } v; v.i = ((u32)u) << 16; return v.f;
}
__device__ __forceinline__ u16 f2bf(float f) {      // hw RNE cvt
    __bf16 h = (__bf16)f; return __builtin_bit_cast(u16, h);
}

// async global->LDS, 16B/lane; lds dest must be wave-uniform base (HW adds lane*16)
__device__ __forceinline__ void gld16(const u16* g, u16* l) {
    __builtin_amdgcn_global_load_lds(
        (const __attribute__((address_space(1))) u32*)g,
        (__attribute__((address_space(3))) u32*)l, 16, 0, 0);
}

// -------------------------------------------------------------------------
// prep: f32 -> bf16 for qx, kvx (into d_out scratch) and the 5 weight mats.
// -------------------------------------------------------------------------
__device__ __forceinline__ void cvt8(const float4* src, u16* dst) {
    float4 a = src[0], b = src[1];
    u16 r[8];
    r[0] = f2bf(a.x); r[1] = f2bf(a.y); r[2] = f2bf(a.z); r[3] = f2bf(a.w);
    r[4] = f2bf(b.x); r[5] = f2bf(b.y); r[6] = f2bf(b.z); r[7] = f2bf(b.w);
    *(uint4*)dst = *(uint4*)r;
}

__global__ __launch_bounds__(256) void prep(
    const float* __restrict__ qx, const float* __restrict__ kvx,
    const float* __restrict__ Wq, const float* __restrict__ Wk,
    const float* __restrict__ Wv, const float* __restrict__ Wg,
    const float* __restrict__ Wo,
    u16* __restrict__ Xq, u16* __restrict__ Xkv, u16* __restrict__ Wball)
{
    const int b = blockIdx.x, t = threadIdx.x;
    if (b < 4096) {
        const int e = (b * 256 + t) * 8;
        cvt8((const float4*)(qx + e), Xq + e);
    } else if (b < 8192) {
        const int e = ((b - 4096) * 256 + t) * 8;
        cvt8((const float4*)(kvx + e), Xkv + e);
    } else {
        const int b2  = b - 8192;            // 0..159: 32 blocks per matrix
        const int mat = b2 >> 5;
        const float* W = (mat == 0) ? Wq : (mat == 1) ? Wk : (mat == 2) ? Wv
                       : (mat == 3) ? Wg : Wo;
        const int off = (b2 & 31) * 2048 + t * 8;
        cvt8((const float4*)(W + off), Wball + mat * 65536 + off);
    }
}

// -------------------------------------------------------------------------
// proj_all: fused Q/K/V/G projections, m97 structure. 2048 blocks.
// Block tile 128x128, BK=64 (4 iters), 4 waves 2x2, wave 64x64 (4x4 frags).
// Swizzle: mb = bid&255 -> 8 A-sharing siblings sit 256 apart == same XCD.
// -------------------------------------------------------------------------
__global__ __launch_bounds__(256) void proj_all(
    const u16* __restrict__ Xq, const u16* __restrict__ Xkv,
    const u16* __restrict__ Wball, const float* __restrict__ bg,
    u16* __restrict__ Qb, u16* __restrict__ Kb, u16* __restrict__ Vb, u16* __restrict__ Gb)
{
    __shared__ u16 At[128 * 64];     // unpadded: required by global_load_lds
    __shared__ u16 Wt[128 * 64];

    const int bid = blockIdx.x;
    const int mb  = bid & 255;
    const int nb  = bid >> 8;        // 0..7
    const int t   = nb >> 1;         // 0=Q 1=K 2=V 3=G
    const int n0  = (nb & 1) * 128;
    const int m0  = mb * 128;
    const u16* A = (t == 0 || t == 3) ? Xq : Xkv;
    const u16* W = Wball + t * 65536;
    u16*       O = (t == 0) ? Qb : (t == 1) ? Kb : (t == 2) ? Vb : Gb;

    const int tid  = threadIdx.x;
    const int lane = tid & 63;
    const int w    = tid >> 6;
    const int quad = lane >> 4;
    const int ln   = lane & 15;
    const int wm   = (w >> 1) * 64;
    const int wn   = (w & 1) * 64;
    const int lrow = lane >> 3;          // 0..7 within an 8-row store group
    const int lcol = (lane & 7) * 8;     // u16 col within row

    f32x4 acc[4][4] = {};

    for (int k0 = 0; k0 < 256; k0 += 64) {
        __syncthreads();                 // prev iter's ds_reads drained
        #pragma unroll
        for (int qq = 0; qq < 4; ++qq) {
            const int r = w * 32 + qq * 8;     // wave-uniform
            gld16(A + (size_t)(m0 + r + lrow) * 256 + k0 + lcol, &At[r * 64]);
            gld16(W + (size_t)(n0 + r + lrow) * 256 + k0 + lcol, &Wt[r * 64]);
        }
        __syncthreads();                 // drains vmcnt: LDS tiles complete

        #pragma unroll
        for (int kk = 0; kk < 2; ++kk) {       // k ascending
            const int kc = kk * 32 + quad * 8;
            bf16x8 af[4], bfr[4];
            #pragma unroll
            for (int i = 0; i < 4; ++i)
                af[i] = __builtin_bit_cast(bf16x8, *(const uint4*)&At[(wm + i * 16 + ln) * 64 + kc]);
            #pragma unroll
            for (int j = 0; j < 4; ++j)
                bfr[j] = __builtin_bit_cast(bf16x8, *(const uint4*)&Wt[(wn + j * 16 + ln) * 64 + kc]);
            #pragma unroll
            for (int i = 0; i < 4; ++i)
                #pragma unroll
                for (int j = 0; j < 4; ++j)
                    acc[i][j] = __builtin_amdgcn_mfma_f32_16x16x32_bf16(af[i], bfr[j], acc[i][j], 0, 0, 0);
        }
    }

    const int act = (t == 3);
    #pragma unroll
    for (int i = 0; i < 4; ++i) {
        #pragma unroll
        for (int j = 0; j < 4; ++j) {
            #pragma unroll
            for (int rr = 0; rr < 4; ++rr) {
                const int row = m0 + wm + i * 16 + quad * 4 + rr;  // C/D row=quad*4+reg
                const int col = n0 + wn + j * 16 + ln;             //     col=lane&15
                float v = acc[i][j][rr];
                if (act) { v += bg[col]; v = 1.0f / (1.0f + __expf(-v)); }
                O[(size_t)row * 256 + col] = f2bf(v);
            }
        }
    }
}

// -------------------------------------------------------------------------
// gemm_out: out = Ob @ Wo^T + bo (f32 out). m97 structure, BM=64 -> 1024
// blocks. Swizzle: m fastest (bid&511) -> n-siblings 512 apart == same XCD.
// -------------------------------------------------------------------------
__global__ __launch_bounds__(256) void gemm_out(
    const u16* __restrict__ Ob, const u16* __restrict__ Wob,
    const float* __restrict__ bo, float* __restrict__ out)
{
    __shared__ u16 At[64 * 64];
    __shared__ u16 Wt[128 * 64];

    const int bid = blockIdx.x;
    const int m0  = (bid & 511) * 64;
    const int n0  = (bid >> 9) * 128;

    const int tid  = threadIdx.x;
    const int lane = tid & 63;
    const int w    = tid >> 6;
    const int quad = lane >> 4;
    const int ln   = lane & 15;
    const int wm   = (w >> 1) * 32;
    const int wn   = (w & 1) * 64;
    const int lrow = lane >> 3;
    const int lcol = (lane & 7) * 8;

    f32x4 acc[2][4] = {};

    for (int k0 = 0; k0 < 256; k0 += 64) {
        __syncthreads();
        #pragma unroll
        for (int qq = 0; qq < 2; ++qq) {
            const int r = w * 16 + qq * 8;
            gld16(Ob + (size_t)(m0 + r + lrow) * 256 + k0 + lcol, &At[r * 64]);
        }
        #pragma unroll
        for (int qq = 0; qq < 4; ++qq) {
            const int r = w * 32 + qq * 8;
            gld16(Wob + (size_t)(n0 + r + lrow) * 256 + k0 + lcol, &Wt[r * 64]);
        }
        __syncthreads();

        #pragma unroll
        for (int kk = 0; kk < 2; ++kk) {
            const int kc = kk * 32 + quad * 8;
            bf16x8 af[2], bfr[4];
            #pragma unroll
            for (int i = 0; i < 2; ++i)
                af[i] = __builtin_bit_cast(bf16x8, *(const uint4*)&At[(wm + i * 16 + ln) * 64 + kc]);
            #pragma unroll
            for (int j = 0; j < 4; ++j)
                bfr[j] = __builtin_bit_cast(bf16x8, *(const uint4*)&Wt[(wn + j * 16 + ln) * 64 + kc]);
            #pragma unroll
            for (int i = 0; i < 2; ++i)
                #pragma unroll
                for (int j = 0; j < 4; ++j)
                    acc[i][j] = __builtin_amdgcn_mfma_f32_16x16x32_bf16(af[i], bfr[j], acc[i][j], 0, 0, 0);
        }
    }

    #pragma unroll
    for (int i = 0; i < 2; ++i) {
        #pragma unroll
        for (int j = 0; j < 4; ++j) {
            #pragma unroll
            for (int rr = 0; rr < 4; ++rr) {
                const int row = m0 + wm + i * 16 + quad * 4 + rr;
                const int col = n0 + wn + j * 16 + ln;
                out[(size_t)row * 256 + col] = acc[i][j][rr] + bo[col];
            }
        }
    }
}

// -------------------------------------------------------------------------
// attn: R5 shape (4096 blocks, one 16-row m-tile per wave). Grid (1024 hs,
// 4 qt): qt-siblings of one (h,s) sit 1024 apart == same XCD (K/V L2 reuse).
// Ob aliases Qb: each block reads Q before writing O at the same addresses;
// (s,q-range,h) ownership is exclusive per block -> no cross-block hazard.
// -------------------------------------------------------------------------
__global__ __launch_bounds__(256) void attn_kernel(
    const u16* __restrict__ Qb, const u16* __restrict__ Kb, const u16* __restrict__ Vb,
    const u16* __restrict__ Gb, const float* __restrict__ bm, const float* __restrict__ bp,
    u16* __restrict__ Ob)
{
    __shared__ u16   Vt[32][264];       // V transposed: Vt[dh][kp]
    __shared__ u16   Pl[4][16][268];    // per-wave P tile
    __shared__ float bmf[256];

    const int hs   = blockIdx.x;
    const int h    = hs & 7;
    const int s    = hs >> 3;
    const int qt   = blockIdx.y;
    const int tid  = threadIdx.x;
    const int lane = tid & 63;
    const int w    = tid >> 6;
    const int quad = lane >> 4;
    const int ln   = lane & 15;

    {   // stage V^T (thread tid = key row) + bias_mask
        const uint4* vp = (const uint4*)(Vb + (size_t)(s * 256 + tid) * 256 + h * 32);
        uint4 vv0 = vp[0], vv1 = vp[1], vv2 = vp[2], vv3 = vp[3];
        u16 tmp[32];
        *(uint4*)&tmp[0]  = vv0; *(uint4*)&tmp[8]  = vv1;
        *(uint4*)&tmp[16] = vv2; *(uint4*)&tmp[24] = vv3;
        #pragma unroll
        for (int dh = 0; dh < 32; ++dh) Vt[dh][tid] = tmp[dh];
        bmf[tid] = bm[s * 256 + tid];
    }
    __syncthreads();

    const int q0 = qt * 64 + w * 16;

    bf16x8 aq = __builtin_bit_cast(bf16x8,
        *(const uint4*)(Qb + (size_t)(s * 256 + q0 + ln) * 256 + h * 32 + quad * 8));

    f32x4 sc[16];
    #pragma unroll
    for (int nt = 0; nt < 16; ++nt) {
        bf16x8 bk = __builtin_bit_cast(bf16x8,
            *(const uint4*)(Kb + (size_t)(s * 256 + nt * 16 + ln) * 256 + h * 32 + quad * 8));
        f32x4 z = {0.f, 0.f, 0.f, 0.f};
        sc[nt] = __builtin_amdgcn_mfma_f32_16x16x32_bf16(aq, bk, z, 0, 0, 0);
    }

    float rmax[4] = {-1e30f, -1e30f, -1e30f, -1e30f};
    #pragma unroll
    for (int nt = 0; nt < 16; ++nt) {
        const int kp = nt * 16 + ln;
        const float bmv = bmf[kp];
        #pragma unroll
        for (int rr = 0; rr < 4; ++rr) {
            const int q = q0 + quad * 4 + rr;
            float v = sc[nt][rr] + bmv + bp[(size_t)(h * 256 + q) * 256 + kp];
            sc[nt][rr] = v;
            rmax[rr] = fmaxf(rmax[rr], v);
        }
    }
    #pragma unroll
    for (int rr = 0; rr < 4; ++rr) {
        float m = rmax[rr];
        m = fmaxf(m, __shfl_xor(m, 1));
        m = fmaxf(m, __shfl_xor(m, 2));
        m = fmaxf(m, __shfl_xor(m, 4));
        m = fmaxf(m, __shfl_xor(m, 8));
        rmax[rr] = m;
    }
    float rsum[4] = {0.f, 0.f, 0.f, 0.f};
    #pragma unroll
    for (int nt = 0; nt < 16; ++nt)
        #pragma unroll
        for (int rr = 0; rr < 4; ++rr) {
            float p = __expf(sc[nt][rr] - rmax[rr]);
            sc[nt][rr] = p;
            rsum[rr] += p;
        }
    float rinv[4];
    #pragma unroll
    for (int rr = 0; rr < 4; ++rr) {
        float t = rsum[rr];
        t += __shfl_xor(t, 1);
        t += __shfl_xor(t, 2);
        t += __shfl_xor(t, 4);
        t += __shfl_xor(t, 8);
        rinv[rr] = 1.0f / t;
    }

    #pragma unroll
    for (int nt = 0; nt < 16; ++nt)
        #pragma unroll
        for (int rr = 0; rr < 4; ++rr)
            Pl[w][quad * 4 + rr][nt * 16 + ln] = f2bf(sc[nt][rr] * rinv[rr]);

    f32x4 o0 = {0.f, 0.f, 0.f, 0.f}, o1 = {0.f, 0.f, 0.f, 0.f};
    #pragma unroll
    for (int kc = 0; kc < 8; ++kc) {
        bf16x8 pa = __builtin_bit_cast(bf16x8, *(const uint4*)&Pl[w][ln][kc * 32 + quad * 8]);
        bf16x8 v0 = __builtin_bit_cast(bf16x8, *(const uint4*)&Vt[ln][kc * 32 + quad * 8]);
        bf16x8 v1 = __builtin_bit_cast(bf16x8, *(const uint4*)&Vt[16 + ln][kc * 32 + quad * 8]);
        o0 = __builtin_amdgcn_mfma_f32_16x16x32_bf16(pa, v0, o0, 0, 0, 0);
        o1 = __builtin_amdgcn_mfma_f32_16x16x32_bf16(pa, v1, o1, 0, 0, 0);
    }

    #pragma unroll
    for (int rr = 0; rr < 4; ++rr) {
        const int q = q0 + quad * 4 + rr;
        const size_t base = (size_t)(s * 256 + q) * 256 + h * 32;
        float g0 = bf2f(Gb[base + ln]);
        float g1 = bf2f(Gb[base + 16 + ln]);
        Ob[base + ln]      = f2bf(o0[rr] * g0);
        Ob[base + 16 + ln] = f2bf(o1[rr] * g1);
    }
}

// -------------------------------------------------------------------------
extern "C" void kernel_launch(void* const* d_in, const int* in_sizes, int n_in,
                              void* d_out, int out_size, void* d_ws, size_t ws_size,
                              hipStream_t stream)
{
    const float* qx  = (const float*)d_in[0];
    const float* kvx = (const float*)d_in[1];
    const float* bm  = (const float*)d_in[2];
    const float* bp  = (const float*)d_in[3];
    const float* Wq  = (const float*)d_in[4];
    const float* Wk  = (const float*)d_in[5];
    const float* Wv  = (const float*)d_in[6];
    const float* Wg  = (const float*)d_in[7];
    const float* bg  = (const float*)d_in[8];
    const float* Wo  = (const float*)d_in[9];
    const float* bo  = (const float*)d_in[10];
    float* out = (float*)d_out;

    // ws: Qb(=Ob), Kb, Vb, Gb (bf16, 16.78 MB each) + bf16 weights (640 KB)
    const size_t NEL = (size_t)32768 * 256;
    u16* Qb = (u16*)d_ws;            // also Ob (attn reads Q before writing O)
    u16* Kb = Qb + NEL;
    u16* Vb = Kb + NEL;
    u16* Gb = Vb + NEL;
    u16* Wball = Gb + NEL;           // 5 * 65536 u16

    // d_out doubles as bf16 scratch for qx/kvx (exact 33.55 MB fit);
    // fully overwritten by gemm_out at the end.
    u16* Xq  = (u16*)d_out;
    u16* Xkv = Xq + NEL;

    prep<<<dim3(8352), dim3(256), 0, stream>>>(qx, kvx, Wq, Wk, Wv, Wg, Wo, Xq, Xkv, Wball);

    proj_all<<<dim3(2048), dim3(256), 0, stream>>>(Xq, Xkv, Wball, bg, Qb, Kb, Vb, Gb);

    attn_kernel<<<dim3(1024, 4), dim3(256), 0, stream>>>(Qb, Kb, Vb, Gb, bm, bp, Qb /*Ob*/);

    gemm_out<<<dim3(1024), dim3(256), 0, stream>>>(Qb /*Ob*/, Wball + 4 * 65536, bo, out);
}

// Round 7
// 229.887 us; speedup vs baseline: 1.2666x; 1.0881x over previous
//
#include <hip/hip_runtime.h>

// Shapes: B=1, S=128, Q=256, C=256, H=8, DH=32, TOT=256. Inputs/out f32.
// Numerics bit-identical to R2-R6 (absmax 0.01953125 vs thr 0.019609).
// R7: head-major intermediate layout Q/K/V/G = [h][s][256][32] so every
// attn access is line-contiguous (R6 FETCH showed 2-4x segment waste on the
// [sq][h*32+dh] layout). O aliases Qh. GEMMs keep m97 global_load_lds.

typedef unsigned short u16;
typedef unsigned int   u32;
typedef float  f32x4  __attribute__((ext_vector_type(4)));
typedef __bf16 bf16x8 __attribute__((ext_vector_type(8)));

__device__ __forceinline__ float bf2f(u16 u) {
    union { u32 i; float f; } v; v.i = ((u32)u) << 16; return v.f;
}
__device__ __forceinline__ u16 f2bf(float f) {      // hw RNE cvt
    __bf16 h = (__bf16)f; return __builtin_bit_cast(u16, h);
}

// async global->LDS, 16B/lane; lds dest wave-uniform base (HW adds lane*16)
__device__ __forceinline__ void gld16(const u16* g, u16* l) {
    __builtin_amdgcn_global_load_lds(
        (const __attribute__((address_space(1))) u32*)g,
        (__attribute__((address_space(3))) u32*)l, 16, 0, 0);
}

// head-major offset for logical (row = s*256+q, col = h*32+dh)
__device__ __forceinline__ size_t hm(int row, int col) {
    const int s = row >> 8, q = row & 255, h = col >> 5, dh = col & 31;
    return ((size_t)((h * 128 + s) * 256 + q) << 5) + dh;
}

// -------------------------------------------------------------------------
// prep: f32 -> bf16 for qx, kvx (into d_out scratch) and the 5 weight mats.
// -------------------------------------------------------------------------
__device__ __forceinline__ void cvt8(const float4* src, u16* dst) {
    float4 a = src[0], b = src[1];
    u16 r[8];
    r[0] = f2bf(a.x); r[1] = f2bf(a.y); r[2] = f2bf(a.z); r[3] = f2bf(a.w);
    r[4] = f2bf(b.x); r[5] = f2bf(b.y); r[6] = f2bf(b.z); r[7] = f2bf(b.w);
    *(uint4*)dst = *(uint4*)r;
}

__global__ __launch_bounds__(256) void prep(
    const float* __restrict__ qx, const float* __restrict__ kvx,
    const float* __restrict__ Wq, const float* __restrict__ Wk,
    const float* __restrict__ Wv, const float* __restrict__ Wg,
    const float* __restrict__ Wo,
    u16* __restrict__ Xq, u16* __restrict__ Xkv, u16* __restrict__ Wball)
{
    const int b = blockIdx.x, t = threadIdx.x;
    if (b < 4096) {
        const int e = (b * 256 + t) * 8;
        cvt8((const float4*)(qx + e), Xq + e);
    } else if (b < 8192) {
        const int e = ((b - 4096) * 256 + t) * 8;
        cvt8((const float4*)(kvx + e), Xkv + e);
    } else {
        const int b2  = b - 8192;            // 0..159: 32 blocks per matrix
        const int mat = b2 >> 5;
        const float* W = (mat == 0) ? Wq : (mat == 1) ? Wk : (mat == 2) ? Wv
                       : (mat == 3) ? Wg : Wo;
        const int off = (b2 & 31) * 2048 + t * 8;
        cvt8((const float4*)(W + off), Wball + mat * 65536 + off);
    }
}

// -------------------------------------------------------------------------
// proj_all: fused Q/K/V/G projections, m97 structure. 2048 blocks.
// Block tile 128x128, BK=64, 4 waves 2x2, wave 64x64 (4x4 frags).
// Swizzle: mb = bid&255 -> 8 A-sharing siblings 256 apart == same XCD.
// Output written HEAD-MAJOR via hm().
// -------------------------------------------------------------------------
__global__ __launch_bounds__(256) void proj_all(
    const u16* __restrict__ Xq, const u16* __restrict__ Xkv,
    const u16* __restrict__ Wball, const float* __restrict__ bg,
    u16* __restrict__ Qh, u16* __restrict__ Kh, u16* __restrict__ Vh, u16* __restrict__ Gh)
{
    __shared__ u16 At[128 * 64];     // unpadded: required by global_load_lds
    __shared__ u16 Wt[128 * 64];

    const int bid = blockIdx.x;
    const int mb  = bid & 255;
    const int nb  = bid >> 8;        // 0..7
    const int t   = nb >> 1;         // 0=Q 1=K 2=V 3=G
    const int n0  = (nb & 1) * 128;
    const int m0  = mb * 128;
    const u16* A = (t == 0 || t == 3) ? Xq : Xkv;
    const u16* W = Wball + t * 65536;
    u16*       O = (t == 0) ? Qh : (t == 1) ? Kh : (t == 2) ? Vh : Gh;

    const int tid  = threadIdx.x;
    const int lane = tid & 63;
    const int w    = tid >> 6;
    const int quad = lane >> 4;
    const int ln   = lane & 15;
    const int wm   = (w >> 1) * 64;
    const int wn   = (w & 1) * 64;
    const int lrow = lane >> 3;          // 0..7
    const int lcol = (lane & 7) * 8;     // u16 col

    f32x4 acc[4][4] = {};

    for (int k0 = 0; k0 < 256; k0 += 64) {
        __syncthreads();
        #pragma unroll
        for (int qq = 0; qq < 4; ++qq) {
            const int r = w * 32 + qq * 8;
            gld16(A + (size_t)(m0 + r + lrow) * 256 + k0 + lcol, &At[r * 64]);
            gld16(W + (size_t)(n0 + r + lrow) * 256 + k0 + lcol, &Wt[r * 64]);
        }
        __syncthreads();

        #pragma unroll
        for (int kk = 0; kk < 2; ++kk) {       // k ascending
            const int kc = kk * 32 + quad * 8;
            bf16x8 af[4], bfr[4];
            #pragma unroll
            for (int i = 0; i < 4; ++i)
                af[i] = __builtin_bit_cast(bf16x8, *(const uint4*)&At[(wm + i * 16 + ln) * 64 + kc]);
            #pragma unroll
            for (int j = 0; j < 4; ++j)
                bfr[j] = __builtin_bit_cast(bf16x8, *(const uint4*)&Wt[(wn + j * 16 + ln) * 64 + kc]);
            #pragma unroll
            for (int i = 0; i < 4; ++i)
                #pragma unroll
                for (int j = 0; j < 4; ++j)
                    acc[i][j] = __builtin_amdgcn_mfma_f32_16x16x32_bf16(af[i], bfr[j], acc[i][j], 0, 0, 0);
        }
    }

    const int act = (t == 3);
    #pragma unroll
    for (int i = 0; i < 4; ++i) {
        #pragma unroll
        for (int j = 0; j < 4; ++j) {
            #pragma unroll
            for (int rr = 0; rr < 4; ++rr) {
                const int row = m0 + wm + i * 16 + quad * 4 + rr;  // C/D row=quad*4+reg
                const int col = n0 + wn + j * 16 + ln;             //     col=lane&15
                float v = acc[i][j][rr];
                if (act) { v += bg[col]; v = 1.0f / (1.0f + __expf(-v)); }
                O[hm(row, col)] = f2bf(v);
            }
        }
    }
}

// -------------------------------------------------------------------------
// gemm_out: out = O @ Wo^T + bo (f32 out). O is head-major (aliases Qh).
// BM=64 -> 1024 blocks. Swizzle: m fastest -> n-siblings 512 apart.
// -------------------------------------------------------------------------
__global__ __launch_bounds__(256) void gemm_out(
    const u16* __restrict__ Oh, const u16* __restrict__ Wob,
    const float* __restrict__ bo, float* __restrict__ out)
{
    __shared__ u16 At[64 * 64];
    __shared__ u16 Wt[128 * 64];

    const int bid = blockIdx.x;
    const int m0  = (bid & 511) * 64;
    const int n0  = (bid >> 9) * 128;

    const int tid  = threadIdx.x;
    const int lane = tid & 63;
    const int w    = tid >> 6;
    const int quad = lane >> 4;
    const int ln   = lane & 15;
    const int wm   = (w >> 1) * 32;
    const int wn   = (w & 1) * 64;
    const int lrow = lane >> 3;
    const int lcol = (lane & 7) * 8;

    f32x4 acc[2][4] = {};

    for (int k0 = 0; k0 < 256; k0 += 64) {
        __syncthreads();
        #pragma unroll
        for (int qq = 0; qq < 2; ++qq) {
            const int r = w * 16 + qq * 8;
            // head-major A: per-lane address from (m, k)
            gld16(Oh + hm(m0 + r + lrow, k0 + lcol), &At[r * 64]);
        }
        #pragma unroll
        for (int qq = 0; qq < 4; ++qq) {
            const int r = w * 32 + qq * 8;
            gld16(Wob + (size_t)(n0 + r + lrow) * 256 + k0 + lcol, &Wt[r * 64]);
        }
        __syncthreads();

        #pragma unroll
        for (int kk = 0; kk < 2; ++kk) {
            const int kc = kk * 32 + quad * 8;
            bf16x8 af[2], bfr[4];
            #pragma unroll
            for (int i = 0; i < 2; ++i)
                af[i] = __builtin_bit_cast(bf16x8, *(const uint4*)&At[(wm + i * 16 + ln) * 64 + kc]);
            #pragma unroll
            for (int j = 0; j < 4; ++j)
                bfr[j] = __builtin_bit_cast(bf16x8, *(const uint4*)&Wt[(wn + j * 16 + ln) * 64 + kc]);
            #pragma unroll
            for (int i = 0; i < 2; ++i)
                #pragma unroll
                for (int j = 0; j < 4; ++j)
                    acc[i][j] = __builtin_amdgcn_mfma_f32_16x16x32_bf16(af[i], bfr[j], acc[i][j], 0, 0, 0);
        }
    }

    #pragma unroll
    for (int i = 0; i < 2; ++i) {
        #pragma unroll
        for (int j = 0; j < 4; ++j) {
            #pragma unroll
            for (int rr = 0; rr < 4; ++rr) {
                const int row = m0 + wm + i * 16 + quad * 4 + rr;
                const int col = n0 + wn + j * 16 + ln;
                out[(size_t)row * 256 + col] = acc[i][j][rr] + bo[col];
            }
        }
    }
}

// -------------------------------------------------------------------------
// attn: 4096 blocks, one 16-row m-tile per wave. Head-major Q/K/V/G: each
// (s,h) slice is a contiguous 16 KB block -> fully coalesced loads.
// Grid (1024 hs, 4 qt): qt-siblings 1024 apart == same XCD (K/V L2 reuse).
// O aliases Qh (head-major): wave reads its own Q tile (register dep chain)
// before writing O at the same addresses; ownership exclusive per wave.
// -------------------------------------------------------------------------
__global__ __launch_bounds__(256) void attn_kernel(
    const u16* __restrict__ Qh, const u16* __restrict__ Kh, const u16* __restrict__ Vh,
    const u16* __restrict__ Gh, const float* __restrict__ bm, const float* __restrict__ bp,
    u16* __restrict__ Oh)
{
    __shared__ u16   Vt[32][264];       // V transposed: Vt[dh][kp]
    __shared__ u16   Pl[4][16][268];    // per-wave P tile
    __shared__ float bmf[256];

    const int hs   = blockIdx.x;
    const int h    = hs & 7;
    const int s    = hs >> 3;
    const int qt   = blockIdx.y;
    const int tid  = threadIdx.x;
    const int lane = tid & 63;
    const int w    = tid >> 6;
    const int quad = lane >> 4;
    const int ln   = lane & 15;

    const size_t hsBase = ((size_t)(h * 128 + s) * 256) << 5;   // start of [h][s] slice

    {   // stage V^T (thread tid = key row; 64 B/thread, block-contiguous 16 KB)
        const uint4* vp = (const uint4*)(Vh + hsBase + (size_t)tid * 32);
        uint4 vv0 = vp[0], vv1 = vp[1], vv2 = vp[2], vv3 = vp[3];
        u16 tmp[32];
        *(uint4*)&tmp[0]  = vv0; *(uint4*)&tmp[8]  = vv1;
        *(uint4*)&tmp[16] = vv2; *(uint4*)&tmp[24] = vv3;
        #pragma unroll
        for (int dh = 0; dh < 32; ++dh) Vt[dh][tid] = tmp[dh];
        bmf[tid] = bm[s * 256 + tid];
    }
    __syncthreads();

    const int q0 = qt * 64 + w * 16;

    bf16x8 aq = __builtin_bit_cast(bf16x8,
        *(const uint4*)(Qh + hsBase + (size_t)(q0 + ln) * 32 + quad * 8));

    f32x4 sc[16];
    #pragma unroll
    for (int nt = 0; nt < 16; ++nt) {
        bf16x8 bk = __builtin_bit_cast(bf16x8,
            *(const uint4*)(Kh + hsBase + (size_t)(nt * 16 + ln) * 32 + quad * 8));
        f32x4 z = {0.f, 0.f, 0.f, 0.f};
        sc[nt] = __builtin_amdgcn_mfma_f32_16x16x32_bf16(aq, bk, z, 0, 0, 0);
    }

    float rmax[4] = {-1e30f, -1e30f, -1e30f, -1e30f};
    #pragma unroll
    for (int nt = 0; nt < 16; ++nt) {
        const int kp = nt * 16 + ln;
        const float bmv = bmf[kp];
        #pragma unroll
        for (int rr = 0; rr < 4; ++rr) {
            const int q = q0 + quad * 4 + rr;
            float v = sc[nt][rr] + bmv + bp[(size_t)(h * 256 + q) * 256 + kp];
            sc[nt][rr] = v;
            rmax[rr] = fmaxf(rmax[rr], v);
        }
    }
    #pragma unroll
    for (int rr = 0; rr < 4; ++rr) {
        float m = rmax[rr];
        m = fmaxf(m, __shfl_xor(m, 1));
        m = fmaxf(m, __shfl_xor(m, 2));
        m = fmaxf(m, __shfl_xor(m, 4));
        m = fmaxf(m, __shfl_xor(m, 8));
        rmax[rr] = m;
    }
    float rsum[4] = {0.f, 0.f, 0.f, 0.f};
    #pragma unroll
    for (int nt = 0; nt < 16; ++nt)
        #pragma unroll
        for (int rr = 0; rr < 4; ++rr) {
            float p = __expf(sc[nt][rr] - rmax[rr]);
            sc[nt][rr] = p;
            rsum[rr] += p;
        }
    float rinv[4];
    #pragma unroll
    for (int rr = 0; rr < 4; ++rr) {
        float t = rsum[rr];
        t += __shfl_xor(t, 1);
        t += __shfl_xor(t, 2);
        t += __shfl_xor(t, 4);
        t += __shfl_xor(t, 8);
        rinv[rr] = 1.0f / t;
    }

    #pragma unroll
    for (int nt = 0; nt < 16; ++nt)
        #pragma unroll
        for (int rr = 0; rr < 4; ++rr)
            Pl[w][quad * 4 + rr][nt * 16 + ln] = f2bf(sc[nt][rr] * rinv[rr]);

    f32x4 o0 = {0.f, 0.f, 0.f, 0.f}, o1 = {0.f, 0.f, 0.f, 0.f};
    #pragma unroll
    for (int kc = 0; kc < 8; ++kc) {
        bf16x8 pa = __builtin_bit_cast(bf16x8, *(const uint4*)&Pl[w][ln][kc * 32 + quad * 8]);
        bf16x8 v0 = __builtin_bit_cast(bf16x8, *(const uint4*)&Vt[ln][kc * 32 + quad * 8]);
        bf16x8 v1 = __builtin_bit_cast(bf16x8, *(const uint4*)&Vt[16 + ln][kc * 32 + quad * 8]);
        o0 = __builtin_amdgcn_mfma_f32_16x16x32_bf16(pa, v0, o0, 0, 0, 0);
        o1 = __builtin_amdgcn_mfma_f32_16x16x32_bf16(pa, v1, o1, 0, 0, 0);
    }

    #pragma unroll
    for (int rr = 0; rr < 4; ++rr) {
        const int q = q0 + quad * 4 + rr;
        const size_t base = hsBase + (size_t)q * 32;
        float g0 = bf2f(Gh[base + ln]);
        float g1 = bf2f(Gh[base + 16 + ln]);
        Oh[base + ln]      = f2bf(o0[rr] * g0);
        Oh[base + 16 + ln] = f2bf(o1[rr] * g1);
    }
}

// -------------------------------------------------------------------------
extern "C" void kernel_launch(void* const* d_in, const int* in_sizes, int n_in,
                              void* d_out, int out_size, void* d_ws, size_t ws_size,
                              hipStream_t stream)
{
    const float* qx  = (const float*)d_in[0];
    const float* kvx = (const float*)d_in[1];
    const float* bm  = (const float*)d_in[2];
    const float* bp  = (const float*)d_in[3];
    const float* Wq  = (const float*)d_in[4];
    const float* Wk  = (const float*)d_in[5];
    const float* Wv  = (const float*)d_in[6];
    const float* Wg  = (const float*)d_in[7];
    const float* bg  = (const float*)d_in[8];
    const float* Wo  = (const float*)d_in[9];
    const float* bo  = (const float*)d_in[10];
    float* out = (float*)d_out;

    // ws: Qh(=Oh), Kh, Vh, Gh (bf16, 16.78 MB each, head-major) + weights
    const size_t NEL = (size_t)32768 * 256;
    u16* Qh = (u16*)d_ws;            // also Oh
    u16* Kh = Qh + NEL;
    u16* Vh = Kh + NEL;
    u16* Gh = Vh + NEL;
    u16* Wball = Gh + NEL;           // 5 * 65536 u16

    // d_out doubles as bf16 scratch for qx/kvx; overwritten by gemm_out.
    u16* Xq  = (u16*)d_out;
    u16* Xkv = Xq + NEL;

    prep<<<dim3(8352), dim3(256), 0, stream>>>(qx, kvx, Wq, Wk, Wv, Wg, Wo, Xq, Xkv, Wball);

    proj_all<<<dim3(2048), dim3(256), 0, stream>>>(Xq, Xkv, Wball, bg, Qh, Kh, Vh, Gh);

    attn_kernel<<<dim3(1024, 4), dim3(256), 0, stream>>>(Qh, Kh, Vh, Gh, bm, bp, Qh /*Oh*/);

    gemm_out<<<dim3(1024), dim3(256), 0, stream>>>(Qh /*Oh*/, Wball + 4 * 65536, bo, out);
}